// Round 4
// baseline (7995.679 us; speedup 1.0000x reference)
//
#include <hip/hip_runtime.h>
#include <math.h>

#define BB 16
#define NN 512   // seq1 rows = columns of the transposed LSA problem
#define MM 448   // seq2 rows = rows of the transposed LSA problem
#define DD 1536

// ---------------------------------------------------------------------------
// Cost kernel: Ct[b][j][i] = ||seq1[b,i,:] - seq2[b,j,:]||  (float32)
// Unchanged from the passing round-1/2 version.
// ---------------------------------------------------------------------------
constexpr int TK = 32;

__global__ __launch_bounds__(256) void cost_kernel(const float* __restrict__ s1,
                                                   const float* __restrict__ s2,
                                                   float* __restrict__ Ct) {
  __shared__ float As[TK][68];
  __shared__ float Bs[TK][68];
  const int b = blockIdx.z;
  const int ibase = blockIdx.x * 64;
  const int jbase = blockIdx.y * 64;
  const int tid = threadIdx.x;
  const float* s1b = s1 + ((size_t)b * NN + ibase) * DD;
  const float* s2b = s2 + ((size_t)b * MM + jbase) * DD;
  const int ix = (tid & 15) * 4;
  const int jy = (tid >> 4) * 4;
  double acc[16];
#pragma unroll
  for (int t = 0; t < 16; ++t) acc[t] = 0.0;

  for (int k0 = 0; k0 < DD; k0 += TK) {
#pragma unroll
    for (int rep = 0; rep < 2; ++rep) {
      int idx = tid + rep * 256;
      int r = idx >> 3;
      int c4 = (idx & 7) * 4;
      float4 a = *(const float4*)(s1b + (size_t)r * DD + k0 + c4);
      As[c4 + 0][r] = a.x; As[c4 + 1][r] = a.y; As[c4 + 2][r] = a.z; As[c4 + 3][r] = a.w;
      float4 bb = *(const float4*)(s2b + (size_t)r * DD + k0 + c4);
      Bs[c4 + 0][r] = bb.x; Bs[c4 + 1][r] = bb.y; Bs[c4 + 2][r] = bb.z; Bs[c4 + 3][r] = bb.w;
    }
    __syncthreads();
    float pacc[16];
#pragma unroll
    for (int t = 0; t < 16; ++t) pacc[t] = 0.f;
#pragma unroll 8
    for (int kk = 0; kk < TK; ++kk) {
      float4 av = *(const float4*)&As[kk][ix];
      float4 bv = *(const float4*)&Bs[kk][jy];
      float a[4] = {av.x, av.y, av.z, av.w};
      float bq[4] = {bv.x, bv.y, bv.z, bv.w};
#pragma unroll
      for (int t = 0; t < 4; ++t)
#pragma unroll
        for (int q = 0; q < 4; ++q) {
          float d = a[t] - bq[q];
          pacc[t * 4 + q] = fmaf(d, d, pacc[t * 4 + q]);
        }
    }
#pragma unroll
    for (int t = 0; t < 16; ++t) acc[t] += (double)pacc[t];
    __syncthreads();
  }
#pragma unroll
  for (int t = 0; t < 4; ++t)
#pragma unroll
    for (int q = 0; q < 4; ++q) {
      int i = ibase + ix + t;
      int jj = jbase + jy + q;
      float d2 = (float)acc[t * 4 + q];
      Ct[((size_t)b * MM + jj) * NN + i] = sqrtf(fmaxf(d2, 0.f));
    }
}

// ---------------------------------------------------------------------------
// Wave-wide min via DPP, broadcast via readlane(63). Bit-exact (min only
// copies bit patterns). f64 version verified rounds 1-2 (absmax = 0).
// ---------------------------------------------------------------------------
__device__ __forceinline__ double wave_min_bcast_f64(double x) {
  union DU { double d; unsigned int u[2]; };
  DU v; v.d = x;
  DU inf; inf.d = 1e18;
#define DPP_STEP(CTRL) { DU o; \
  o.u[0] = (unsigned)__builtin_amdgcn_update_dpp((int)inf.u[0], (int)v.u[0], CTRL, 0xF, 0xF, false); \
  o.u[1] = (unsigned)__builtin_amdgcn_update_dpp((int)inf.u[1], (int)v.u[1], CTRL, 0xF, 0xF, false); \
  if (o.d < v.d) v.d = o.d; }
  DPP_STEP(0x111)  // row_shr:1
  DPP_STEP(0x112)  // row_shr:2
  DPP_STEP(0x114)  // row_shr:4
  DPP_STEP(0x118)  // row_shr:8
  DPP_STEP(0x142)  // row_bcast:15
  DPP_STEP(0x143)  // row_bcast:31
#undef DPP_STEP
  DU r;
  r.u[0] = (unsigned)__builtin_amdgcn_readlane((int)v.u[0], 63);
  r.u[1] = (unsigned)__builtin_amdgcn_readlane((int)v.u[1], 63);
  return r.d;
}

__device__ __forceinline__ float wave_min_bcast_f32(float x) {
  union FU { float f; int i; };
  FU v; v.f = x;
  const int INFB = 0x7f7fffff;   // FLT_MAX bit pattern
#define DPP1(CTRL) { FU o; \
  o.i = __builtin_amdgcn_update_dpp(INFB, v.i, CTRL, 0xF, 0xF, false); \
  if (o.f < v.f) v.f = o.f; }
  DPP1(0x111) DPP1(0x112) DPP1(0x114) DPP1(0x118) DPP1(0x142) DPP1(0x143)
#undef DPP1
  FU r; r.i = __builtin_amdgcn_readlane(v.i, 63);
  return r.f;
}

// ---------------------------------------------------------------------------
// JV solver, ONE WAVE per batch.
// Phase 1 (ROW reduction — rectangular-valid, unlike R3's column reduction):
//   u[i] = min_j c[i][j] (exact f32 => exact tightness/feasibility), v = 0.
//   Row i claims its argmin column; lowest row wins (serial, race-free).
//   Duals satisfy ALL rectangular-LP invariants: feasibility, tightness on
//   matched edges, v <= 0, v = 0 on unmatched columns. Unmatched columns are
//   never popped by a Dijkstra (a popped unmatched column ends the Dijkstra
//   and becomes matched), so v stays 0 on them => final matching optimal.
// Phase 3: Dijkstra/augment inner loop BYTE-IDENTICAL to the round-2
//   verified version; only the u init and the matched-row skip differ.
// ---------------------------------------------------------------------------
__global__ __launch_bounds__(64) void jv_kernel(const float* __restrict__ Ct,
                                                int* __restrict__ perm) {
  const int b = blockIdx.x;
  const float* C = Ct + (size_t)b * MM * NN;
  __shared__ double u_lds[MM + 1];
  __shared__ int p_lds[NN + 1];
  __shared__ int way_lds[NN + 1];
  __shared__ int colOwner[NN];
  __shared__ int rowMatched[MM];
  __shared__ int cnt_lds[64];
  const int lane = threadIdx.x;
  const int jbase = 8 * lane + 1;   // owned columns, 1-based

  if (lane == 0) u_lds[0] = 0.0;
  for (int t = lane; t <= NN; t += 64) { p_lds[t] = 0; way_lds[t] = 0; }
  for (int t = lane; t < NN; t += 64) colOwner[t] = -1;
  for (int t = lane; t < MM; t += 64) rowMatched[t] = 0;
  asm volatile("s_waitcnt lgkmcnt(0)" ::: "memory");

  // ---- Phase 1: row reduction + greedy claim ----
  for (int r = 0; r < MM; ++r) {
    const float4* r4 = (const float4*)(C + (size_t)r * NN);
    float4 ca = r4[2 * lane];
    float4 cb = r4[2 * lane + 1];
    float c[8] = {ca.x, ca.y, ca.z, ca.w, cb.x, cb.y, cb.z, cb.w};
    float lm = 1e30f; int la = 0;
#pragma unroll
    for (int q = 0; q < 8; ++q)
      if (c[q] < lm) { lm = c[q]; la = 8 * lane + q; }   // lowest col in lane
    float rm = wave_min_bcast_f32(lm);
    unsigned long long bm = __ballot(lm == rm);
    int sl = (int)__ffsll((unsigned long long)bm) - 1;    // lowest lane w/ min
    int jc = __builtin_amdgcn_readlane(la, sl);           // 0-based argmin col
    if (lane == 0) {
      u_lds[r + 1] = (double)rm;
      if (colOwner[jc] < 0) {       // first (lowest) row wins the column
        colOwner[jc] = r;
        rowMatched[r] = 1;
        p_lds[jc + 1] = r + 1;
      }
    }
  }
  double vcol[8];
#pragma unroll
  for (int q = 0; q < 8; ++q) vcol[q] = 0.0;
  asm volatile("s_waitcnt lgkmcnt(0)" ::: "memory");

  // ---- Phase 3: augment free rows (round-2 verified inner loop) ----
  for (int i = 1; i <= MM; ++i) {
    if (rowMatched[i - 1]) continue;
    if (lane == 0) p_lds[0] = i;
    double minv[8], rec[8];
    int preg[8];
#pragma unroll
    for (int q = 0; q < 8; ++q) { minv[q] = 1e18; rec[q] = 0.0; preg[q] = 0; }
    int usedm = 0;
    double cum = 0.0;
    int j0 = 0, i0 = i;

    while (true) {
#pragma unroll
      for (int q = 0; q < 8; ++q)
        if (j0 == jbase + q) { usedm |= (1 << q); preg[q] = i0; rec[q] = cum; }

      const float4* r4 = (const float4*)(C + (size_t)(i0 - 1) * NN);
      float4 ca = r4[2 * lane];
      float4 cb = r4[2 * lane + 1];
      double uu = u_lds[i0];
      float c[8] = {ca.x, ca.y, ca.z, ca.w, cb.x, cb.y, cb.z, cb.w};
#pragma unroll
      for (int q = 0; q < 8; ++q) {
        if (!((usedm >> q) & 1)) {
          double cur = ((double)c[q] - uu) - vcol[q];
          if (cur < minv[q]) { minv[q] = cur; way_lds[jbase + q] = j0; }
        }
      }
      double cand = 1e18; int argj = 0;
#pragma unroll
      for (int q = 0; q < 8; ++q) {
        double mq = ((usedm >> q) & 1) ? 1e18 : minv[q];
        if (mq < cand) { cand = mq; argj = jbase + q; }
      }
      double delta = wave_min_bcast_f64(cand);
      unsigned long long bm = __ballot(cand == delta);
      int sl = (int)__ffsll((unsigned long long)bm) - 1;
      int j1 = __builtin_amdgcn_readlane(argj, sl);
      cum += delta;
#pragma unroll
      for (int q = 0; q < 8; ++q)
        if (!((usedm >> q) & 1)) minv[q] -= delta;
      int pn = p_lds[j1];
      j0 = j1;
      if (pn == 0) break;
      i0 = pn;
    }

    if (lane == 0) u_lds[i] += cum;
#pragma unroll
    for (int q = 0; q < 8; ++q)
      if ((usedm >> q) & 1) {
        double d = cum - rec[q];
        vcol[q] -= d;
        u_lds[preg[q]] += d;   // popped rows are distinct -> no conflicts
      }
    asm volatile("s_waitcnt lgkmcnt(0)" ::: "memory");
    if (lane == 0) {
      int jj = j0;
      while (jj != 0) { int jp = way_lds[jj]; p_lds[jj] = p_lds[jp]; jj = jp; }
    }
    asm volatile("s_waitcnt lgkmcnt(0)" ::: "memory");
  }

  // perm = matched cols (assigned seq1 rows) ascending, then unmatched ascending
  int mask = 0, cnt = 0;
#pragma unroll
  for (int q = 0; q < 8; ++q)
    if (p_lds[jbase + q] != 0) { mask |= 1 << q; cnt++; }
  cnt_lds[lane] = cnt;
  asm volatile("s_waitcnt lgkmcnt(0)" ::: "memory");
  int pre = 0;
  for (int l = 0; l < 64; ++l) { int cl = cnt_lds[l]; if (l < lane) pre += cl; }
  int mpos = pre;
  int upos = MM + (8 * lane - pre);
#pragma unroll
  for (int q = 0; q < 8; ++q) {
    int col = 8 * lane + q;
    if ((mask >> q) & 1) perm[b * NN + mpos++] = col;
    else                 perm[b * NN + upos++] = col;
  }
}

// ---------------------------------------------------------------------------
// Gather: out[b,i,:] = seq1[b, perm[b][i], :]
// ---------------------------------------------------------------------------
__global__ __launch_bounds__(256) void gather_kernel(const float* __restrict__ s1,
                                                     const int* __restrict__ perm,
                                                     float* __restrict__ out) {
  const int bi = blockIdx.x;
  const int b = bi >> 9;
  const int src = perm[bi];
  const float4* sp = (const float4*)(s1 + ((size_t)b * NN + src) * DD);
  float4* dp = (float4*)(out + (size_t)bi * DD);
  for (int t = threadIdx.x; t < DD / 4; t += 256) dp[t] = sp[t];
}

extern "C" void kernel_launch(void* const* d_in, const int* in_sizes, int n_in,
                              void* d_out, int out_size, void* d_ws, size_t ws_size,
                              hipStream_t stream) {
  const float* s1 = (const float*)d_in[0];
  const float* s2 = (const float*)d_in[1];
  float* out = (float*)d_out;
  float* Ct = (float*)d_out;       // staged cost matrix, overwritten by gather
  int* perm = (int*)d_ws;

  dim3 cg(NN / 64, MM / 64, BB);
  cost_kernel<<<cg, 256, 0, stream>>>(s1, s2, Ct);
  jv_kernel<<<BB, 64, 0, stream>>>(Ct, perm);
  gather_kernel<<<BB * NN, 256, 0, stream>>>(s1, perm, out);
}

// Round 5
// 7232.769 us; speedup vs baseline: 1.1055x; 1.1055x over previous
//
#include <hip/hip_runtime.h>
#include <math.h>

#define BB 16
#define NN 512   // seq1 rows = columns of the transposed LSA problem
#define MM 448   // seq2 rows = rows of the transposed LSA problem
#define DD 1536

// ---------------------------------------------------------------------------
// Cost kernel: Ct[b][j][i] = ||seq1[b,i,:] - seq2[b,j,:]||  (float32)
// Unchanged from the passing round-1/2/4 version.
// ---------------------------------------------------------------------------
constexpr int TK = 32;

__global__ __launch_bounds__(256) void cost_kernel(const float* __restrict__ s1,
                                                   const float* __restrict__ s2,
                                                   float* __restrict__ Ct) {
  __shared__ float As[TK][68];
  __shared__ float Bs[TK][68];
  const int b = blockIdx.z;
  const int ibase = blockIdx.x * 64;
  const int jbase = blockIdx.y * 64;
  const int tid = threadIdx.x;
  const float* s1b = s1 + ((size_t)b * NN + ibase) * DD;
  const float* s2b = s2 + ((size_t)b * MM + jbase) * DD;
  const int ix = (tid & 15) * 4;
  const int jy = (tid >> 4) * 4;
  double acc[16];
#pragma unroll
  for (int t = 0; t < 16; ++t) acc[t] = 0.0;

  for (int k0 = 0; k0 < DD; k0 += TK) {
#pragma unroll
    for (int rep = 0; rep < 2; ++rep) {
      int idx = tid + rep * 256;
      int r = idx >> 3;
      int c4 = (idx & 7) * 4;
      float4 a = *(const float4*)(s1b + (size_t)r * DD + k0 + c4);
      As[c4 + 0][r] = a.x; As[c4 + 1][r] = a.y; As[c4 + 2][r] = a.z; As[c4 + 3][r] = a.w;
      float4 bb = *(const float4*)(s2b + (size_t)r * DD + k0 + c4);
      Bs[c4 + 0][r] = bb.x; Bs[c4 + 1][r] = bb.y; Bs[c4 + 2][r] = bb.z; Bs[c4 + 3][r] = bb.w;
    }
    __syncthreads();
    float pacc[16];
#pragma unroll
    for (int t = 0; t < 16; ++t) pacc[t] = 0.f;
#pragma unroll 8
    for (int kk = 0; kk < TK; ++kk) {
      float4 av = *(const float4*)&As[kk][ix];
      float4 bv = *(const float4*)&Bs[kk][jy];
      float a[4] = {av.x, av.y, av.z, av.w};
      float bq[4] = {bv.x, bv.y, bv.z, bv.w};
#pragma unroll
      for (int t = 0; t < 4; ++t)
#pragma unroll
        for (int q = 0; q < 4; ++q) {
          float d = a[t] - bq[q];
          pacc[t * 4 + q] = fmaf(d, d, pacc[t * 4 + q]);
        }
    }
#pragma unroll
    for (int t = 0; t < 16; ++t) acc[t] += (double)pacc[t];
    __syncthreads();
  }
#pragma unroll
  for (int t = 0; t < 4; ++t)
#pragma unroll
    for (int q = 0; q < 4; ++q) {
      int i = ibase + ix + t;
      int jj = jbase + jy + q;
      float d2 = (float)acc[t * 4 + q];
      Ct[((size_t)b * MM + jj) * NN + i] = sqrtf(fmaxf(d2, 0.f));
    }
}

// ---------------------------------------------------------------------------
// Wave-wide min via DPP, broadcast via readlane(63). Bit-exact (min copies
// bit patterns). Verified rounds 1-4 (absmax = 0).
// ---------------------------------------------------------------------------
__device__ __forceinline__ double wave_min_bcast_f64(double x) {
  union DU { double d; unsigned int u[2]; };
  DU v; v.d = x;
  DU inf; inf.d = 1e18;
#define DPP_STEP(CTRL) { DU o; \
  o.u[0] = (unsigned)__builtin_amdgcn_update_dpp((int)inf.u[0], (int)v.u[0], CTRL, 0xF, 0xF, false); \
  o.u[1] = (unsigned)__builtin_amdgcn_update_dpp((int)inf.u[1], (int)v.u[1], CTRL, 0xF, 0xF, false); \
  if (o.d < v.d) v.d = o.d; }
  DPP_STEP(0x111)  // row_shr:1
  DPP_STEP(0x112)  // row_shr:2
  DPP_STEP(0x114)  // row_shr:4
  DPP_STEP(0x118)  // row_shr:8
  DPP_STEP(0x142)  // row_bcast:15
  DPP_STEP(0x143)  // row_bcast:31
#undef DPP_STEP
  DU r;
  r.u[0] = (unsigned)__builtin_amdgcn_readlane((int)v.u[0], 63);
  r.u[1] = (unsigned)__builtin_amdgcn_readlane((int)v.u[1], 63);
  return r.d;
}

__device__ __forceinline__ float wave_min_bcast_f32(float x) {
  union FU { float f; int i; };
  FU v; v.f = x;
  const int INFB = 0x7f7fffff;   // FLT_MAX bit pattern
#define DPP1(CTRL) { FU o; \
  o.i = __builtin_amdgcn_update_dpp(INFB, v.i, CTRL, 0xF, 0xF, false); \
  if (o.f < v.f) v.f = o.f; }
  DPP1(0x111) DPP1(0x112) DPP1(0x114) DPP1(0x118) DPP1(0x142) DPP1(0x143)
#undef DPP1
  FU r; r.i = __builtin_amdgcn_readlane(v.i, 63);
  return r.f;
}

// ---------------------------------------------------------------------------
// Full Jonker-Volgenant, ONE WAVE per batch.
// Phase 1: row reduction u[i]=rowmin (exact f32), greedy claim (R4-verified).
// Phase 2 (NEW): augmenting row reduction, 2 passes. For each free row:
//   umin/usubmin of reduced cost; claim argmin col j1; strict win lowers
//   v[j1] by (usub-umin) and re-processes the kicked owner immediately;
//   tie win kicks owner into the next pass. All rectangular-LP invariants
//   hold: v only decreases and only on matched columns, claimed edges tight
//   (u[i]=usub), feasibility preserved, v=0 on unmatched columns.
// Phase 3: Dijkstra/augment loop byte-identical to R2/R4-verified version,
//   over the post-ARR free list.
// ---------------------------------------------------------------------------
__global__ __launch_bounds__(64) void jv_kernel(const float* __restrict__ Ct,
                                                int* __restrict__ perm) {
  const int b = blockIdx.x;
  const float* C = Ct + (size_t)b * MM * NN;
  __shared__ double u_lds[MM + 1];
  __shared__ int p_lds[NN + 1];
  __shared__ int way_lds[NN + 1];
  __shared__ int colOwner[NN];
  __shared__ int rowMatched[MM];
  __shared__ int freeL[MM];
  __shared__ int nfree_s;
  __shared__ int cnt_lds[64];
  const int lane = threadIdx.x;
  const int jbase = 8 * lane + 1;   // owned columns, 1-based

  if (lane == 0) u_lds[0] = 0.0;
  for (int t = lane; t <= NN; t += 64) { p_lds[t] = 0; way_lds[t] = 0; }
  for (int t = lane; t < NN; t += 64) colOwner[t] = -1;
  for (int t = lane; t < MM; t += 64) rowMatched[t] = 0;
  asm volatile("s_waitcnt lgkmcnt(0)" ::: "memory");

  // ---- Phase 1: row reduction + greedy claim (R4-verified) ----
  for (int r = 0; r < MM; ++r) {
    const float4* r4 = (const float4*)(C + (size_t)r * NN);
    float4 ca = r4[2 * lane];
    float4 cb = r4[2 * lane + 1];
    float c[8] = {ca.x, ca.y, ca.z, ca.w, cb.x, cb.y, cb.z, cb.w};
    float lm = 1e30f; int la = 0;
#pragma unroll
    for (int q = 0; q < 8; ++q)
      if (c[q] < lm) { lm = c[q]; la = 8 * lane + q; }
    float rm = wave_min_bcast_f32(lm);
    unsigned long long bm = __ballot(lm == rm);
    int sl = (int)__ffsll((unsigned long long)bm) - 1;
    int jc = __builtin_amdgcn_readlane(la, sl);
    if (lane == 0) {
      u_lds[r + 1] = (double)rm;
      if (colOwner[jc] < 0) {
        colOwner[jc] = r;
        rowMatched[r] = 1;
        p_lds[jc + 1] = r + 1;
      }
    }
  }
  double vcol[8];
#pragma unroll
  for (int q = 0; q < 8; ++q) vcol[q] = 0.0;
  asm volatile("s_waitcnt lgkmcnt(0)" ::: "memory");

  // ---- build free list (ascending) ----
  if (lane == 0) {
    int n = 0;
    for (int r = 0; r < MM; ++r) if (!rowMatched[r]) freeL[n++] = r;
    nfree_s = n;
  }
  asm volatile("s_waitcnt lgkmcnt(0)" ::: "memory");
  int nfree = nfree_s;   // same LDS addr in all lanes -> uniform

  // ---- Phase 2: augmenting row reduction, 2 passes ----
  for (int pass = 0; pass < 2; ++pass) {
    int prev = nfree; nfree = 0; int k = 0;
    while (k < prev) {
      const int i = freeL[k]; k++;     // uniform LDS read
      const float4* r4 = (const float4*)(C + (size_t)i * NN);
      float4 ca = r4[2 * lane];
      float4 cb = r4[2 * lane + 1];
      float c[8] = {ca.x, ca.y, ca.z, ca.w, cb.x, cb.y, cb.z, cb.w};
      double m1 = 1e18, m2 = 1e18; int a1 = 0;
#pragma unroll
      for (int q = 0; q < 8; ++q) {
        double h = (double)c[q] - vcol[q];
        if (h < m1) { m2 = m1; m1 = h; a1 = 8 * lane + q; }
        else if (h < m2) m2 = h;
      }
      double umin = wave_min_bcast_f64(m1);
      unsigned long long bm = __ballot(m1 == umin);
      int sl = (int)__ffsll((unsigned long long)bm) - 1;
      int j1 = __builtin_amdgcn_readlane(a1, sl);   // 0-based column
      double cd = (lane == sl) ? m2 : m1;
      double usub = wave_min_bcast_f64(cd);
      const bool strict = (umin < usub);
      if (strict && (j1 >> 3) == lane) {
        double dec = usub - umin;
#pragma unroll
        for (int qq = 0; qq < 8; ++qq) if (qq == (j1 & 7)) vcol[qq] -= dec;
      }
      const int powner = p_lds[j1 + 1];             // uniform read (pre-write)
      asm volatile("" ::: "memory");                // keep read before write
      const int i0 = powner - 1;
      if (lane == 0) { u_lds[i + 1] = usub; p_lds[j1 + 1] = i + 1; }
      if (i0 >= 0) {
        if (strict) { k--; if (lane == 0) freeL[k] = i0; }   // re-process now
        else        { if (lane == 0) freeL[nfree] = i0; nfree++; }
      }
      asm volatile("s_waitcnt lgkmcnt(0)" ::: "memory");
    }
  }

  // ---- Phase 3: Dijkstra/augment for remaining free rows (R2-verified) ----
  const int nf3 = nfree;
  for (int fi = 0; fi < nf3; ++fi) {
    const int i = freeL[fi] + 1;   // 1-based row
    if (lane == 0) p_lds[0] = i;
    double minv[8], rec[8];
    int preg[8];
#pragma unroll
    for (int q = 0; q < 8; ++q) { minv[q] = 1e18; rec[q] = 0.0; preg[q] = 0; }
    int usedm = 0;
    double cum = 0.0;
    int j0 = 0, i0 = i;

    while (true) {
#pragma unroll
      for (int q = 0; q < 8; ++q)
        if (j0 == jbase + q) { usedm |= (1 << q); preg[q] = i0; rec[q] = cum; }

      const float4* r4 = (const float4*)(C + (size_t)(i0 - 1) * NN);
      float4 ca = r4[2 * lane];
      float4 cb = r4[2 * lane + 1];
      double uu = u_lds[i0];
      float c[8] = {ca.x, ca.y, ca.z, ca.w, cb.x, cb.y, cb.z, cb.w};
#pragma unroll
      for (int q = 0; q < 8; ++q) {
        if (!((usedm >> q) & 1)) {
          double cur = ((double)c[q] - uu) - vcol[q];
          if (cur < minv[q]) { minv[q] = cur; way_lds[jbase + q] = j0; }
        }
      }
      double cand = 1e18; int argj = 0;
#pragma unroll
      for (int q = 0; q < 8; ++q) {
        double mq = ((usedm >> q) & 1) ? 1e18 : minv[q];
        if (mq < cand) { cand = mq; argj = jbase + q; }
      }
      double delta = wave_min_bcast_f64(cand);
      unsigned long long bm = __ballot(cand == delta);
      int sl = (int)__ffsll((unsigned long long)bm) - 1;
      int j1 = __builtin_amdgcn_readlane(argj, sl);
      cum += delta;
#pragma unroll
      for (int q = 0; q < 8; ++q)
        if (!((usedm >> q) & 1)) minv[q] -= delta;
      int pn = p_lds[j1];
      j0 = j1;
      if (pn == 0) break;
      i0 = pn;
    }

    if (lane == 0) u_lds[i] += cum;
#pragma unroll
    for (int q = 0; q < 8; ++q)
      if ((usedm >> q) & 1) {
        double d = cum - rec[q];
        vcol[q] -= d;
        u_lds[preg[q]] += d;   // popped rows distinct -> no conflicts
      }
    asm volatile("s_waitcnt lgkmcnt(0)" ::: "memory");
    if (lane == 0) {
      int jj = j0;
      while (jj != 0) { int jp = way_lds[jj]; p_lds[jj] = p_lds[jp]; jj = jp; }
    }
    asm volatile("s_waitcnt lgkmcnt(0)" ::: "memory");
  }

  // perm = matched cols (assigned seq1 rows) ascending, then unmatched ascending
  int mask = 0, cnt = 0;
#pragma unroll
  for (int q = 0; q < 8; ++q)
    if (p_lds[jbase + q] != 0) { mask |= 1 << q; cnt++; }
  cnt_lds[lane] = cnt;
  asm volatile("s_waitcnt lgkmcnt(0)" ::: "memory");
  int pre = 0;
  for (int l = 0; l < 64; ++l) { int cl = cnt_lds[l]; if (l < lane) pre += cl; }
  int mpos = pre;
  int upos = MM + (8 * lane - pre);
#pragma unroll
  for (int q = 0; q < 8; ++q) {
    int col = 8 * lane + q;
    if ((mask >> q) & 1) perm[b * NN + mpos++] = col;
    else                 perm[b * NN + upos++] = col;
  }
}

// ---------------------------------------------------------------------------
// Gather: out[b,i,:] = seq1[b, perm[b][i], :]
// ---------------------------------------------------------------------------
__global__ __launch_bounds__(256) void gather_kernel(const float* __restrict__ s1,
                                                     const int* __restrict__ perm,
                                                     float* __restrict__ out) {
  const int bi = blockIdx.x;
  const int b = bi >> 9;
  const int src = perm[bi];
  const float4* sp = (const float4*)(s1 + ((size_t)b * NN + src) * DD);
  float4* dp = (float4*)(out + (size_t)bi * DD);
  for (int t = threadIdx.x; t < DD / 4; t += 256) dp[t] = sp[t];
}

extern "C" void kernel_launch(void* const* d_in, const int* in_sizes, int n_in,
                              void* d_out, int out_size, void* d_ws, size_t ws_size,
                              hipStream_t stream) {
  const float* s1 = (const float*)d_in[0];
  const float* s2 = (const float*)d_in[1];
  float* out = (float*)d_out;
  float* Ct = (float*)d_out;       // staged cost matrix, overwritten by gather
  int* perm = (int*)d_ws;

  dim3 cg(NN / 64, MM / 64, BB);
  cost_kernel<<<cg, 256, 0, stream>>>(s1, s2, Ct);
  jv_kernel<<<BB, 64, 0, stream>>>(Ct, perm);
  gather_kernel<<<BB * NN, 256, 0, stream>>>(s1, perm, out);
}

// Round 6
// 6793.620 us; speedup vs baseline: 1.1769x; 1.0646x over previous
//
#include <hip/hip_runtime.h>
#include <math.h>

#define BB 16
#define NN 512   // seq1 rows = columns of the transposed LSA problem
#define MM 448   // seq2 rows = rows of the transposed LSA problem
#define DD 1536

// ---------------------------------------------------------------------------
// Cost kernel: Ct[b][j][i] = ||seq1[b,i,:] - seq2[b,j,:]||  (float32)
// Unchanged from the passing round-1/2/4/5 version.
// ---------------------------------------------------------------------------
constexpr int TK = 32;

__global__ __launch_bounds__(256) void cost_kernel(const float* __restrict__ s1,
                                                   const float* __restrict__ s2,
                                                   float* __restrict__ Ct) {
  __shared__ float As[TK][68];
  __shared__ float Bs[TK][68];
  const int b = blockIdx.z;
  const int ibase = blockIdx.x * 64;
  const int jbase = blockIdx.y * 64;
  const int tid = threadIdx.x;
  const float* s1b = s1 + ((size_t)b * NN + ibase) * DD;
  const float* s2b = s2 + ((size_t)b * MM + jbase) * DD;
  const int ix = (tid & 15) * 4;
  const int jy = (tid >> 4) * 4;
  double acc[16];
#pragma unroll
  for (int t = 0; t < 16; ++t) acc[t] = 0.0;

  for (int k0 = 0; k0 < DD; k0 += TK) {
#pragma unroll
    for (int rep = 0; rep < 2; ++rep) {
      int idx = tid + rep * 256;
      int r = idx >> 3;
      int c4 = (idx & 7) * 4;
      float4 a = *(const float4*)(s1b + (size_t)r * DD + k0 + c4);
      As[c4 + 0][r] = a.x; As[c4 + 1][r] = a.y; As[c4 + 2][r] = a.z; As[c4 + 3][r] = a.w;
      float4 bb = *(const float4*)(s2b + (size_t)r * DD + k0 + c4);
      Bs[c4 + 0][r] = bb.x; Bs[c4 + 1][r] = bb.y; Bs[c4 + 2][r] = bb.z; Bs[c4 + 3][r] = bb.w;
    }
    __syncthreads();
    float pacc[16];
#pragma unroll
    for (int t = 0; t < 16; ++t) pacc[t] = 0.f;
#pragma unroll 8
    for (int kk = 0; kk < TK; ++kk) {
      float4 av = *(const float4*)&As[kk][ix];
      float4 bv = *(const float4*)&Bs[kk][jy];
      float a[4] = {av.x, av.y, av.z, av.w};
      float bq[4] = {bv.x, bv.y, bv.z, bv.w};
#pragma unroll
      for (int t = 0; t < 4; ++t)
#pragma unroll
        for (int q = 0; q < 4; ++q) {
          float d = a[t] - bq[q];
          pacc[t * 4 + q] = fmaf(d, d, pacc[t * 4 + q]);
        }
    }
#pragma unroll
    for (int t = 0; t < 16; ++t) acc[t] += (double)pacc[t];
    __syncthreads();
  }
#pragma unroll
  for (int t = 0; t < 4; ++t)
#pragma unroll
    for (int q = 0; q < 4; ++q) {
      int i = ibase + ix + t;
      int jj = jbase + jy + q;
      float d2 = (float)acc[t * 4 + q];
      Ct[((size_t)b * MM + jj) * NN + i] = sqrtf(fmaxf(d2, 0.f));
    }
}

// ---------------------------------------------------------------------------
// Cross-lane reduction primitives (DPP shr 1/2/4/8 + bcast 15/31, readlane 63
// broadcast — control pattern verified bit-exact in rounds 1-5, absmax = 0).
// ---------------------------------------------------------------------------
__device__ __forceinline__ unsigned wave_min_bcast_u32(unsigned x) {
  int v = (int)x;
#define ST(C) { int o = __builtin_amdgcn_update_dpp(-1, v, C, 0xF, 0xF, false); \
                v = ((unsigned)o < (unsigned)v) ? o : v; }
  ST(0x111) ST(0x112) ST(0x114) ST(0x118) ST(0x142) ST(0x143)
#undef ST
  return (unsigned)__builtin_amdgcn_readlane(v, 63);
}

// Exact f64 min over the wave for NONNEGATIVE doubles: bit pattern of a
// nonneg double is order-preserving as u64 -> two u32 min stages (hi, then
// lo among hi-winners). ~2x shorter dependent chain than cmp/cndmask f64 DPP.
__device__ __forceinline__ double wave_min_bcast_f64_fast(double x) {
  union DU { double d; unsigned u[2]; };
  DU v; v.d = x;
  unsigned hmin = wave_min_bcast_u32(v.u[1]);
  unsigned lc = (v.u[1] == hmin) ? v.u[0] : 0xFFFFFFFFu;
  unsigned lmin = wave_min_bcast_u32(lc);
  DU r; r.u[0] = lmin; r.u[1] = hmin;
  return r.d;
}

__device__ __forceinline__ float wave_min_bcast_f32(float x) {
  union FU { float f; int i; };
  FU v; v.f = x;
  const int INFB = 0x7f7fffff;   // FLT_MAX bit pattern
#define DPP1(CTRL) { FU o; \
  o.i = __builtin_amdgcn_update_dpp(INFB, v.i, CTRL, 0xF, 0xF, false); \
  if (o.f < v.f) v.f = o.f; }
  DPP1(0x111) DPP1(0x112) DPP1(0x114) DPP1(0x118) DPP1(0x142) DPP1(0x143)
#undef DPP1
  FU r; r.i = __builtin_amdgcn_readlane(v.i, 63);
  return r.f;
}

// ---------------------------------------------------------------------------
// Full Jonker-Volgenant, ONE WAVE per batch.
// Phase 1: row reduction u[i]=rowmin (exact f32), greedy claim (R4-verified).
// Phase 2: augmenting row reduction, 2 passes (R5-verified; reduce swapped
//   for the bit-exact fast version).
// Phase 3: Dijkstra/augment with latency-optimized pop:
//   - reduced costs clamped >= 0 (exact-math invariant; enables u32 reduce)
//   - used columns folded into minv = 1e18 -> mask-free tree argmin
//   - speculative per-lane p_lds[local_argmin] prefetch during the reduce
// Dual-update semantics identical to the R2/R4/R5-verified deferred scheme.
// ---------------------------------------------------------------------------
__global__ __launch_bounds__(64) void jv_kernel(const float* __restrict__ Ct,
                                                int* __restrict__ perm) {
  const int b = blockIdx.x;
  const float* C = Ct + (size_t)b * MM * NN;
  __shared__ double u_lds[MM + 1];
  __shared__ int p_lds[NN + 1];
  __shared__ int way_lds[NN + 1];
  __shared__ int colOwner[NN];
  __shared__ int rowMatched[MM];
  __shared__ int freeL[MM];
  __shared__ int nfree_s;
  __shared__ int cnt_lds[64];
  const int lane = threadIdx.x;
  const int jbase = 8 * lane + 1;   // owned columns, 1-based

  if (lane == 0) u_lds[0] = 0.0;
  for (int t = lane; t <= NN; t += 64) { p_lds[t] = 0; way_lds[t] = 0; }
  for (int t = lane; t < NN; t += 64) colOwner[t] = -1;
  for (int t = lane; t < MM; t += 64) rowMatched[t] = 0;
  asm volatile("s_waitcnt lgkmcnt(0)" ::: "memory");

  // ---- Phase 1: row reduction + greedy claim ----
  for (int r = 0; r < MM; ++r) {
    const float4* r4 = (const float4*)(C + (size_t)r * NN);
    float4 ca = r4[2 * lane];
    float4 cb = r4[2 * lane + 1];
    float c[8] = {ca.x, ca.y, ca.z, ca.w, cb.x, cb.y, cb.z, cb.w};
    float lm = 1e30f; int la = 0;
#pragma unroll
    for (int q = 0; q < 8; ++q)
      if (c[q] < lm) { lm = c[q]; la = 8 * lane + q; }
    float rm = wave_min_bcast_f32(lm);
    unsigned long long bm = __ballot(lm == rm);
    int sl = (int)__ffsll((unsigned long long)bm) - 1;
    int jc = __builtin_amdgcn_readlane(la, sl);
    if (lane == 0) {
      u_lds[r + 1] = (double)rm;
      if (colOwner[jc] < 0) {
        colOwner[jc] = r;
        rowMatched[r] = 1;
        p_lds[jc + 1] = r + 1;
      }
    }
  }
  double vcol[8];
#pragma unroll
  for (int q = 0; q < 8; ++q) vcol[q] = 0.0;
  asm volatile("s_waitcnt lgkmcnt(0)" ::: "memory");

  // ---- build free list (ascending) ----
  if (lane == 0) {
    int n = 0;
    for (int r = 0; r < MM; ++r) if (!rowMatched[r]) freeL[n++] = r;
    nfree_s = n;
  }
  asm volatile("s_waitcnt lgkmcnt(0)" ::: "memory");
  int nfree = nfree_s;   // same LDS addr in all lanes -> uniform

  // ---- Phase 2: augmenting row reduction, 2 passes ----
  for (int pass = 0; pass < 2; ++pass) {
    int prev = nfree; nfree = 0; int k = 0;
    while (k < prev) {
      const int i = freeL[k]; k++;     // uniform LDS read
      const float4* r4 = (const float4*)(C + (size_t)i * NN);
      float4 ca = r4[2 * lane];
      float4 cb = r4[2 * lane + 1];
      float c[8] = {ca.x, ca.y, ca.z, ca.w, cb.x, cb.y, cb.z, cb.w};
      double m1 = 1e18, m2 = 1e18; int a1 = 0;
#pragma unroll
      for (int q = 0; q < 8; ++q) {
        double h = (double)c[q] - vcol[q];   // v <= 0, c >= 0 -> h >= 0
        if (h < m1) { m2 = m1; m1 = h; a1 = 8 * lane + q; }
        else if (h < m2) m2 = h;
      }
      double umin = wave_min_bcast_f64_fast(m1);
      unsigned long long bm = __ballot(m1 == umin);
      int sl = (int)__ffsll((unsigned long long)bm) - 1;
      int j1 = __builtin_amdgcn_readlane(a1, sl);   // 0-based column
      double cd = (lane == sl) ? m2 : m1;
      double usub = wave_min_bcast_f64_fast(cd);
      const bool strict = (umin < usub);
      if (strict && (j1 >> 3) == lane) {
        double dec = usub - umin;
#pragma unroll
        for (int qq = 0; qq < 8; ++qq) if (qq == (j1 & 7)) vcol[qq] -= dec;
      }
      const int powner = p_lds[j1 + 1];             // uniform read (pre-write)
      asm volatile("" ::: "memory");                // keep read before write
      const int i0 = powner - 1;
      if (lane == 0) { u_lds[i + 1] = usub; p_lds[j1 + 1] = i + 1; }
      if (i0 >= 0) {
        if (strict) { k--; if (lane == 0) freeL[k] = i0; }   // re-process now
        else        { if (lane == 0) freeL[nfree] = i0; nfree++; }
      }
      asm volatile("s_waitcnt lgkmcnt(0)" ::: "memory");
    }
  }

  // ---- Phase 3: Dijkstra/augment for remaining free rows ----
  const int nf3 = nfree;
  for (int fi = 0; fi < nf3; ++fi) {
    const int i = freeL[fi] + 1;   // 1-based row
    if (lane == 0) p_lds[0] = i;   // augment terminator: p[0] = current row
    double minv[8], rec[8];
    int preg[8];
#pragma unroll
    for (int q = 0; q < 8; ++q) { minv[q] = 1e18; rec[q] = 0.0; preg[q] = 0; }
    int usedm = 0;
    double cum = 0.0;
    int j0 = 0, i0 = i;
    asm volatile("s_waitcnt lgkmcnt(0)" ::: "memory");

    while (true) {
      // mark column j0 used; minv -> +inf removes it from the argmin tree
#pragma unroll
      for (int q = 0; q < 8; ++q)
        if (j0 == jbase + q) {
          usedm |= (1 << q); preg[q] = i0; rec[q] = cum; minv[q] = 1e18;
        }

      const float4* r4 = (const float4*)(C + (size_t)(i0 - 1) * NN);
      float4 ca = r4[2 * lane];
      float4 cb = r4[2 * lane + 1];
      double uu = u_lds[i0];
      float c[8] = {ca.x, ca.y, ca.z, ca.w, cb.x, cb.y, cb.z, cb.w};
#pragma unroll
      for (int q = 0; q < 8; ++q) {
        if (!((usedm >> q) & 1)) {
          double cur = ((double)c[q] - uu) - vcol[q];
          cur = (cur > 0.0) ? cur : 0.0;   // exact-math nonneg; clamp noise
          if (cur < minv[q]) { minv[q] = cur; way_lds[jbase + q] = j0; }
        }
      }
      // mask-free tree argmin over 8 (strict < keeps lowest index)
      double m01 = (minv[1] < minv[0]) ? minv[1] : minv[0];
      int    a01 = (minv[1] < minv[0]) ? jbase + 1 : jbase + 0;
      double m23 = (minv[3] < minv[2]) ? minv[3] : minv[2];
      int    a23 = (minv[3] < minv[2]) ? jbase + 3 : jbase + 2;
      double m45 = (minv[5] < minv[4]) ? minv[5] : minv[4];
      int    a45 = (minv[5] < minv[4]) ? jbase + 5 : jbase + 4;
      double m67 = (minv[7] < minv[6]) ? minv[7] : minv[6];
      int    a67 = (minv[7] < minv[6]) ? jbase + 7 : jbase + 6;
      double m03 = (m23 < m01) ? m23 : m01;
      int    a03 = (m23 < m01) ? a23 : a01;
      double m47 = (m67 < m45) ? m67 : m45;
      int    a47 = (m67 < m45) ? a67 : a45;
      double lm = (m47 < m03) ? m47 : m03;
      int    la = (m47 < m03) ? a47 : a03;

      // speculative owner prefetch (p is constant within one Dijkstra)
      int pcand = p_lds[la];

      // two-stage exact u32 reduce (values nonneg or 1e18 sentinel)
      union DU { double d; unsigned u[2]; };
      DU lv; lv.d = lm;
      unsigned hmin = wave_min_bcast_u32(lv.u[1]);
      unsigned lc = (lv.u[1] == hmin) ? lv.u[0] : 0xFFFFFFFFu;
      unsigned lmin = wave_min_bcast_u32(lc);
      unsigned long long bm = __ballot((lv.u[1] == hmin) && (lv.u[0] == lmin));
      int sl = (int)__ffsll((unsigned long long)bm) - 1;
      int j1 = __builtin_amdgcn_readlane(la, sl);
      int pn = __builtin_amdgcn_readlane(pcand, sl);
      DU dd; dd.u[0] = lmin; dd.u[1] = hmin;
      double delta = dd.d;
      cum += delta;
#pragma unroll
      for (int q = 0; q < 8; ++q) minv[q] -= delta;   // 1e18 absorbs delta
      j0 = j1;
      if (pn == 0) break;
      i0 = pn;
    }

    if (lane == 0) u_lds[i] += cum;
#pragma unroll
    for (int q = 0; q < 8; ++q)
      if ((usedm >> q) & 1) {
        double d = cum - rec[q];
        vcol[q] -= d;
        u_lds[preg[q]] += d;   // popped rows distinct -> no conflicts
      }
    asm volatile("s_waitcnt lgkmcnt(0)" ::: "memory");
    if (lane == 0) {
      int jj = j0;
      while (jj != 0) { int jp = way_lds[jj]; p_lds[jj] = p_lds[jp]; jj = jp; }
    }
    asm volatile("s_waitcnt lgkmcnt(0)" ::: "memory");
  }

  // perm = matched cols (assigned seq1 rows) ascending, then unmatched ascending
  int mask = 0, cnt = 0;
#pragma unroll
  for (int q = 0; q < 8; ++q)
    if (p_lds[jbase + q] != 0) { mask |= 1 << q; cnt++; }
  cnt_lds[lane] = cnt;
  asm volatile("s_waitcnt lgkmcnt(0)" ::: "memory");
  int pre = 0;
  for (int l = 0; l < 64; ++l) { int cl = cnt_lds[l]; if (l < lane) pre += cl; }
  int mpos = pre;
  int upos = MM + (8 * lane - pre);
#pragma unroll
  for (int q = 0; q < 8; ++q) {
    int col = 8 * lane + q;
    if ((mask >> q) & 1) perm[b * NN + mpos++] = col;
    else                 perm[b * NN + upos++] = col;
  }
}

// ---------------------------------------------------------------------------
// Gather: out[b,i,:] = seq1[b, perm[b][i], :]
// ---------------------------------------------------------------------------
__global__ __launch_bounds__(256) void gather_kernel(const float* __restrict__ s1,
                                                     const int* __restrict__ perm,
                                                     float* __restrict__ out) {
  const int bi = blockIdx.x;
  const int b = bi >> 9;
  const int src = perm[bi];
  const float4* sp = (const float4*)(s1 + ((size_t)b * NN + src) * DD);
  float4* dp = (float4*)(out + (size_t)bi * DD);
  for (int t = threadIdx.x; t < DD / 4; t += 256) dp[t] = sp[t];
}

extern "C" void kernel_launch(void* const* d_in, const int* in_sizes, int n_in,
                              void* d_out, int out_size, void* d_ws, size_t ws_size,
                              hipStream_t stream) {
  const float* s1 = (const float*)d_in[0];
  const float* s2 = (const float*)d_in[1];
  float* out = (float*)d_out;
  float* Ct = (float*)d_out;       // staged cost matrix, overwritten by gather
  int* perm = (int*)d_ws;

  dim3 cg(NN / 64, MM / 64, BB);
  cost_kernel<<<cg, 256, 0, stream>>>(s1, s2, Ct);
  jv_kernel<<<BB, 64, 0, stream>>>(Ct, perm);
  gather_kernel<<<BB * NN, 256, 0, stream>>>(s1, perm, out);
}